// Round 1
// baseline (345.087 us; speedup 1.0000x reference)
//
#include <hip/hip_runtime.h>
#include <stdint.h>

// Problem constants (fixed by the reference)
#define C_IN   96
#define KIN    768      // 8*C
#define NOUT   192
#define MTILE  32       // tokens per block (= one (b,d,h) row, w=0..31)
#define LDK    776      // KIN + 8 bf16 pad -> row stride 1552 B, bank shift 4 (<=2-way, free)
#define EPS    1e-5f

typedef __bf16 bf16x8 __attribute__((ext_vector_type(8)));
typedef float  f32x4  __attribute__((ext_vector_type(4)));

static __device__ __forceinline__ unsigned int f2bf(float f) {
    union { float f; unsigned int u; } v; v.f = f;
    // round-to-nearest-even bf16, returned in low 16 bits
    return (v.u + 0x7fffu + ((v.u >> 16) & 1u)) >> 16;
}
static __device__ __forceinline__ float bf2f(unsigned int s) {
    union { unsigned int u; float f; } v; v.u = s << 16;
    return v.f;
}
static __device__ __forceinline__ unsigned int normpack(unsigned int p, float mu, float rs) {
    float lo = (bf2f(p & 0xffffu) - mu) * rs;
    float hi = (bf2f(p >> 16)     - mu) * rs;
    return f2bf(lo) | (f2bf(hi) << 16);
}

// ---------------------------------------------------------------------------
// Prep: W'[o][c] = bf16(W[o][c] * ln_w[c]);  bias[o] = sum_c ln_b[c]*W[o][c]
// Folds the LN affine into the linear layer: out = yhat . W'^T + bias.
// ---------------------------------------------------------------------------
__global__ __launch_bounds__(256) void prep_kernel(
    const float* __restrict__ W, const float* __restrict__ lnw,
    const float* __restrict__ lnb, unsigned short* __restrict__ Wb,
    float* __restrict__ bias)
{
    int o = blockIdx.x;
    int tid = threadIdx.x;
    float part = 0.f;
    for (int c = tid; c < KIN; c += 256) {
        float w = W[(size_t)o * KIN + c];
        Wb[(size_t)o * KIN + c] = (unsigned short)f2bf(w * lnw[c]);
        part += w * lnb[c];
    }
    #pragma unroll
    for (int m = 32; m >= 1; m >>= 1) part += __shfl_xor(part, m, 64);
    __shared__ float red[4];
    if ((tid & 63) == 0) red[tid >> 6] = part;
    __syncthreads();
    if (tid == 0) bias[o] = red[0] + red[1] + red[2] + red[3];
}

// ---------------------------------------------------------------------------
// Fused gather + LayerNorm + GEMM (bf16 MFMA 16x16x32)
// Block: 256 threads (4 waves), 32 tokens. Token t = ((b*32+d)*32+h)*32+w.
// ---------------------------------------------------------------------------
__global__ __launch_bounds__(256) void merge_kernel(
    const float* __restrict__ x, const unsigned short* __restrict__ Wb,
    const float* __restrict__ bias, float* __restrict__ out)
{
    __shared__ unsigned short ylds[MTILE * LDK];   // 49664 B
    __shared__ float muL[MTILE], rsL[MTILE];

    const int tid   = threadIdx.x;
    const int tbase = blockIdx.x * MTILE;
    const int bh = blockIdx.x;                 // = (b*32+d)*32 + h
    const int h  = bh & 31;
    const int d  = (bh >> 5) & 31;
    const int b  = bh >> 10;

    // ---- Phase 1: gather fp32 -> bf16 LDS, fp32 stats in flight -------------
    const int tk = tid >> 3;   // token in tile == w coordinate
    const int i  = tid & 7;    // sub-lane within token
    float sum = 0.f, sq = 0.f;
    #pragma unroll
    for (int g = 0; g < 8; ++g) {
        const int s0 = g >> 2, s1 = (g >> 1) & 1, s2 = g & 1;
        const float* src = x +
            ((size_t)((b * 64 + 2 * d + s0) * 64 + (2 * h + s1)) * 64 + (2 * tk + s2)) * C_IN;
        #pragma unroll
        for (int jj = 0; jj < 3; ++jj) {
            const int c4 = i + jj * 8;                 // float4 index within the 96-float run
            float4 v = *(const float4*)(src + c4 * 4); // 8 lanes -> 128 B contiguous
            sum += v.x + v.y + v.z + v.w;
            sq  += v.x * v.x + v.y * v.y + v.z * v.z + v.w * v.w;
            uint2 p;
            p.x = f2bf(v.x) | (f2bf(v.y) << 16);
            p.y = f2bf(v.z) | (f2bf(v.w) << 16);
            *(uint2*)&ylds[tk * LDK + g * 96 + c4 * 4] = p;
        }
    }
    // width-8 butterfly: all 8 lanes of a token share the totals
    #pragma unroll
    for (int m = 4; m >= 1; m >>= 1) {
        sum += __shfl_xor(sum, m, 8);
        sq  += __shfl_xor(sq,  m, 8);
    }
    if (i == 0) {
        float mean = sum * (1.f / 768.f);
        float var  = sq * (1.f / 768.f) - mean * mean;
        muL[tk] = mean;
        rsL[tk] = rsqrtf(var + EPS);
    }
    __syncthreads();

    // ---- Phase 2: normalize LDS in place (contiguous 96-elem segment/lane) --
    {
        const float mu = muL[tk], rs = rsL[tk];
        unsigned short* row = &ylds[tk * LDK + i * 96];
        #pragma unroll
        for (int jj = 0; jj < 12; ++jj) {
            uint4 u = *(const uint4*)(row + jj * 8);
            u.x = normpack(u.x, mu, rs);
            u.y = normpack(u.y, mu, rs);
            u.z = normpack(u.z, mu, rs);
            u.w = normpack(u.w, mu, rs);
            *(uint4*)(row + jj * 8) = u;
        }
    }
    __syncthreads();

    // ---- Phase 3: GEMM  C[32 x 192] = Yhat[32 x 768] . W'^T -----------------
    // wave w handles N columns [w*48, w*48+48): 2 M-tiles x 3 N-tiles of 16x16
    const int wv    = tid >> 6;
    const int l     = tid & 63;
    const int l15   = l & 15;
    const int quad  = l >> 4;
    const int nbase = wv * 48;
    const int koff  = quad * 8;

    f32x4 acc[2][3];
    #pragma unroll
    for (int mt = 0; mt < 2; ++mt)
        #pragma unroll
        for (int nt = 0; nt < 3; ++nt)
            acc[mt][nt] = (f32x4){0.f, 0.f, 0.f, 0.f};

    const unsigned short* arow0 = &ylds[(l15)      * LDK + koff];
    const unsigned short* arow1 = &ylds[(16 + l15) * LDK + koff];
    const unsigned short* brow0 = Wb + (size_t)(nbase +  0 + l15) * KIN + koff;
    const unsigned short* brow1 = Wb + (size_t)(nbase + 16 + l15) * KIN + koff;
    const unsigned short* brow2 = Wb + (size_t)(nbase + 32 + l15) * KIN + koff;

    #pragma unroll
    for (int kk = 0; kk < 24; ++kk) {
        const int k = kk * 32;
        bf16x8 a0 = *(const bf16x8*)(arow0 + k);   // ds_read_b128
        bf16x8 a1 = *(const bf16x8*)(arow1 + k);
        bf16x8 b0 = *(const bf16x8*)(brow0 + k);   // global dwordx4, L2-hot
        bf16x8 b1 = *(const bf16x8*)(brow1 + k);
        bf16x8 b2 = *(const bf16x8*)(brow2 + k);
        acc[0][0] = __builtin_amdgcn_mfma_f32_16x16x32_bf16(a0, b0, acc[0][0], 0, 0, 0);
        acc[0][1] = __builtin_amdgcn_mfma_f32_16x16x32_bf16(a0, b1, acc[0][1], 0, 0, 0);
        acc[0][2] = __builtin_amdgcn_mfma_f32_16x16x32_bf16(a0, b2, acc[0][2], 0, 0, 0);
        acc[1][0] = __builtin_amdgcn_mfma_f32_16x16x32_bf16(a1, b0, acc[1][0], 0, 0, 0);
        acc[1][1] = __builtin_amdgcn_mfma_f32_16x16x32_bf16(a1, b1, acc[1][1], 0, 0, 0);
        acc[1][2] = __builtin_amdgcn_mfma_f32_16x16x32_bf16(a1, b2, acc[1][2], 0, 0, 0);
    }

    // ---- Epilogue: D row = quad*4 + r, col = l15; add fused bias ------------
    const float b0 = bias[nbase + l15];
    const float b1 = bias[nbase + 16 + l15];
    const float b2 = bias[nbase + 32 + l15];
    #pragma unroll
    for (int mt = 0; mt < 2; ++mt) {
        #pragma unroll
        for (int r = 0; r < 4; ++r) {
            const int row = mt * 16 + quad * 4 + r;
            float* op = out + (size_t)(tbase + row) * NOUT + nbase + l15;
            op[0]  = acc[mt][0][r] + b0;
            op[16] = acc[mt][1][r] + b1;
            op[32] = acc[mt][2][r] + b2;
        }
    }
}

// ---------------------------------------------------------------------------
extern "C" void kernel_launch(void* const* d_in, const int* in_sizes, int n_in,
                              void* d_out, int out_size, void* d_ws, size_t ws_size,
                              hipStream_t stream) {
    const float* x   = (const float*)d_in[0];
    const float* lnw = (const float*)d_in[1];
    const float* lnb = (const float*)d_in[2];
    const float* W   = (const float*)d_in[3];
    float* out = (float*)d_out;

    unsigned short* Wb = (unsigned short*)d_ws;                       // 192*768*2 B
    float* bias = (float*)((char*)d_ws + (size_t)NOUT * KIN * 2);     // 192*4 B

    prep_kernel<<<NOUT, 256, 0, stream>>>(W, lnw, lnb, Wb, bias);
    merge_kernel<<<2048, 256, 0, stream>>>(x, Wb, bias, out);
}